// Round 9
// baseline (192.793 us; speedup 1.0000x reference)
//
#include <hip/hip_runtime.h>
#include <math.h>

namespace {
constexpr int B    = 4;
constexpr int N    = 8192;
constexpr int P    = 2048;
constexpr int C    = 128;
constexpr int COUT = 256;
constexpr int NS   = 32;
constexpr int BP   = B * P;     // 8192
constexpr int BPB  = 2;         // bp per group
constexpr int GRP  = 8;         // groups per block
constexpr int NBLK = BP / (BPB * GRP); // 512 x-blocks; grid is (512, 2) cout-halves

// k_prep grid: 2048 transpose + 160 wswz + 1 shift
constexpr int PREP_T = 2048;
constexpr int PREP_W = 160;
constexpr int PREP_NB = PREP_T + PREP_W + 1;   // 2209

// ---- workspace layout (bytes, all 256-aligned) ----
constexpr size_t OFF_FEATT = 0;                          // B*N*C bf16    = 8388608
constexpr size_t OFF_WSWZ  = 8388608;                    // 40960 bf16    = 81920
constexpr size_t OFF_NXD   = 8470528;                    // 8192*3 f64    = 196608
constexpr size_t OFF_NXF   = 8667136;                    // 8192*3 f32    = 98304
constexpr size_t OFF_IDX   = 8765440;                    // 8192*32 i32   = 1048576
constexpr size_t OFF_YMAX  = 9814016;                    // 8192*256 f32  = 8388608
constexpr size_t OFF_PART  = 18202624;                   // 512*512 f32   = 1048576
constexpr size_t OFF_AB    = 19251200;                   // 512 f32       = 2048
constexpr size_t WS_NEED   = 19253248;                   // ~18.4 MB
} // namespace

typedef short bf16x8 __attribute__((ext_vector_type(8)));
typedef float f32x4  __attribute__((ext_vector_type(4)));

typedef const __attribute__((address_space(1))) void gas_void;
typedef __attribute__((address_space(3))) void las_void;
#define GLOBAL_LOAD_LDS16(gp, lp) \
    __builtin_amdgcn_global_load_lds((gas_void*)(gp), (las_void*)(lp), 16, 0, 0)

__device__ inline unsigned short f2bf(float f) {
    unsigned u = __float_as_uint(f);
    unsigned r = u + 0x7fffu + ((u >> 16) & 1u);
    return (unsigned short)(r >> 16);
}

// ---------------- K0: fused prep (all branches PARALLEL — R7 lesson) ----------------
__global__ __launch_bounds__(256) void k_prep(const float* __restrict__ feat,
                                              unsigned short* __restrict__ featT,
                                              const float* __restrict__ wml,
                                              unsigned short* __restrict__ wswz,
                                              const float* __restrict__ ffps,
                                              const float* __restrict__ wsh,
                                              const float* __restrict__ gam,
                                              const float* __restrict__ bet,
                                              double* __restrict__ nxd,
                                              float* __restrict__ nxf) {
    __shared__ float tile[64][33];         // transpose path
    __shared__ double red2[6][4];          // shift path (per-wave partials)
    __shared__ double par2[6];
    int bi = blockIdx.x, t = threadIdx.x;

    if (bi < PREP_T) {
        // ---- transpose: tile 32 n x 64 c ----
        int tx = t & 31, ty = t >> 5;              // 32 x 8
        int n0 = (bi & 255) * 32;
        int rest = bi >> 8;
        int c0 = (rest & 1) * 64, b = rest >> 1;
        const float* src = feat + ((size_t)b * C + c0) * N + n0;
#pragma unroll
        for (int j = 0; j < 8; j++) tile[ty + 8 * j][tx] = src[(size_t)(ty + 8 * j) * N + tx];
        __syncthreads();
#pragma unroll
        for (int j = 0; j < 4; j++) {
            int n = ty + 8 * j;
            unsigned v = (unsigned)f2bf(tile[2 * tx][n]) | ((unsigned)f2bf(tile[2 * tx + 1][n]) << 16);
            *(unsigned*)&featT[((size_t)b * N + n0 + n) * C + c0 + 2 * tx] = v;
        }
    } else if (bi < PREP_T + PREP_W) {
        // ---- wswz (parallel): wswz[rt(16)][ks(5)][lane(64)][j(8)] = W[rt*16+(lane&15)][k'],
        // k' = ks*32+(lane>>4)*8+j; map: k'<128 -> col 3+k'; 128..130 -> col 0..2; else 0
        int i = (bi - PREP_T) * 256 + t;           // < 40960
        int j = i & 7;
        int lane = (i >> 3) & 63;
        int rest = i >> 9;
        int ks = rest % 5, rt = rest / 5;
        int cout = rt * 16 + (lane & 15);
        int k = ks * 32 + (lane >> 4) * 8 + j;
        float v = 0.f;
        if (k < 128) v = wml[cout * 131 + 3 + k];
        else if (k < 131) v = wml[cout * 131 + (k - 128)];
        wswz[i] = f2bf(v);
    } else {
#pragma clang fp contract(off)
        // ---- shift: 256 threads x 32 pts, loads batched x8 so latency pipelines ----
        int lane = t & 63, w = t >> 6;
        double wv[9];
#pragma unroll
        for (int i = 0; i < 9; i++) wv[i] = (double)wsh[i];
        double s[3] = {0, 0, 0}, sq[3] = {0, 0, 0};
        for (int bb = 0; bb < 4; bb++) {
            float f[8][3];
#pragma unroll
            for (int i = 0; i < 8; i++) {
                int p = t + 256 * (bb * 8 + i);
                f[i][0] = ffps[p * 3 + 0]; f[i][1] = ffps[p * 3 + 1]; f[i][2] = ffps[p * 3 + 2];
            }
#pragma unroll
            for (int i = 0; i < 8; i++) {
                double f0 = (double)f[i][0], f1 = (double)f[i][1], f2 = (double)f[i][2];
#pragma unroll
                for (int o = 0; o < 3; o++) {
                    double xo = (wv[o * 3 + 0] * f0 + wv[o * 3 + 1] * f1) + wv[o * 3 + 2] * f2;
                    s[o] += xo;
                    sq[o] += xo * xo;
                }
            }
        }
#pragma unroll
        for (int st = 1; st < 64; st <<= 1) {
#pragma unroll
            for (int o = 0; o < 3; o++) {
                s[o] += __shfl_xor(s[o], st, 64);
                sq[o] += __shfl_xor(sq[o], st, 64);
            }
        }
        if (lane == 0) {
#pragma unroll
            for (int o = 0; o < 3; o++) { red2[o][w] = s[o]; red2[3 + o][w] = sq[o]; }
        }
        __syncthreads();
        if (t == 0) {
#pragma unroll
            for (int o = 0; o < 3; o++) {
                double sm = ((red2[o][0] + red2[o][1]) + (red2[o][2] + red2[o][3]));
                double sqs = ((red2[3 + o][0] + red2[3 + o][1]) + (red2[3 + o][2] + red2[3 + o][3]));
                double m = sm / (double)BP;
                double v = sqs / (double)BP - m * m;
                par2[o] = m;
                par2[3 + o] = 1.0 / sqrt(v + 1e-5);
            }
        }
        __syncthreads();
        double gv[3] = {(double)gam[0], (double)gam[1], (double)gam[2]};
        double bv[3] = {(double)bet[0], (double)bet[1], (double)bet[2]};
        for (int bb = 0; bb < 4; bb++) {
            float f[8][3];
#pragma unroll
            for (int i = 0; i < 8; i++) {
                int p = t + 256 * (bb * 8 + i);
                f[i][0] = ffps[p * 3 + 0]; f[i][1] = ffps[p * 3 + 1]; f[i][2] = ffps[p * 3 + 2];
            }
#pragma unroll
            for (int i = 0; i < 8; i++) {
                int p = t + 256 * (bb * 8 + i);
                double f0 = (double)f[i][0], f1 = (double)f[i][1], f2 = (double)f[i][2];
#pragma unroll
                for (int o = 0; o < 3; o++) {
                    double xo = (wv[o * 3 + 0] * f0 + wv[o * 3 + 1] * f1) + wv[o * 3 + 2] * f2;
                    double y = ((xo - par2[o]) * par2[3 + o]) * gv[o] + bv[o];
                    y = (y > 0.0) ? y : 0.0;
                    nxd[p * 3 + o] = y;
                    nxf[p * 3 + o] = (float)y;
                }
            }
        }
    }
}

// ---------------- K2: ball query, 8-chunk batched + prefetch pipeline ----------------
__global__ __launch_bounds__(256) void k_ballq(const float* __restrict__ bbxyz,
                                               const double* __restrict__ nxd,
                                               int* __restrict__ idxo) {
#pragma clang fp contract(off)
    int t = threadIdx.x;
    int wv = t >> 6, lane = t & 63;
    int q = blockIdx.x * 4 + wv;                   // bp index
    int b = q >> 11;                               // P = 2048
    double qx = nxd[q * 3 + 0], qy = nxd[q * 3 + 1], qz = nxd[q * 3 + 2];
    const double R2 = 0.8 * 0.8;
    // early-out: ball misses backbone cube [-1,1]^3 -> zero neighbors -> pad idx 0
    {
        double ex = fmax(fmax(qx - 1.0, -1.0 - qx), 0.0);
        double ey = fmax(fmax(qy - 1.0, -1.0 - qy), 0.0);
        double ez = fmax(fmax(qz - 1.0, -1.0 - qz), 0.0);
        if (ex * ex + ey * ey + ez * ez >= R2) {
            if (lane < NS) idxo[q * NS + lane] = 0;
            return;
        }
    }
    const float* base = bbxyz + (size_t)b * N * 3;
    int found = 0, firstn = -1;

    float px[8], py[8], pz[8];
#pragma unroll
    for (int j = 0; j < 8; j++) {
        int n = j * 64 + lane;
        px[j] = base[n * 3 + 0]; py[j] = base[n * 3 + 1]; pz[j] = base[n * 3 + 2];
    }
    for (int cb = 0; cb < 16; cb++) {
        float nx[8], ny[8], nz[8];
        int nb = (cb + 1 < 16) ? (cb + 1) * 512 : 0;   // clamped -> unconditional prefetch
#pragma unroll
        for (int j = 0; j < 8; j++) {
            int n = nb + j * 64 + lane;
            nx[j] = base[n * 3 + 0]; ny[j] = base[n * 3 + 1]; nz[j] = base[n * 3 + 2];
        }
#pragma unroll
        for (int j = 0; j < 8; j++) {
            int n = cb * 512 + j * 64 + lane;
            double dx = qx - (double)px[j], dy = qy - (double)py[j], dz = qz - (double)pz[j];
            double d2 = (dx * dx + dy * dy) + dz * dz;
            bool within = d2 < R2;
            unsigned long long mask = __ballot(within);
            if (firstn < 0 && mask != 0ull) firstn = (n - lane) + (__ffsll(mask) - 1);
            if (within) {
                int rank = found + __popcll(mask & ((1ull << lane) - 1ull));
                if (rank < NS) idxo[q * NS + rank] = n;
            }
            found += __popcll(mask);
        }
        if (found >= NS) break;
#pragma unroll
        for (int j = 0; j < 8; j++) { px[j] = nx[j]; py[j] = ny[j]; pz[j] = nz[j]; }
    }
    if (found < NS) {
        int padv = (found == 0) ? 0 : firstn;
        if (lane >= found && lane < NS) idxo[q * NS + lane] = padv;
    }
}

// ---------------- K3: MFMA grouped 1x1 conv, cout-split for occupancy --------------
// Grid (512, 2): x = 16-bp group, y = cout half (128 couts). Block = 4 waves, wave w
// owns couts h*128 + w*32 .. +31 (nt=2). Register footprint: wreg[5][2]=40 +
// acc[4][2]=32 + transients ~= 120 -> launch_bounds(256,4) fits 4 waves/SIMD ->
// 4 blocks/CU (R8: 17% MfmaUtil, 55% stall at 2 blocks/CU -- TLP was the limiter,
// not MFMA/LDS throughput). Staging duplicated across halves (L2-hit gathers, cheap).
__global__ __launch_bounds__(256, 4) void k_mlp_mfma(
        const float* __restrict__ bbxyz,
        const unsigned short* __restrict__ featT,
        const unsigned short* __restrict__ wswz,
        const float* __restrict__ nxf,
        const int* __restrict__ idx,
        float* __restrict__ ymax,
        float* __restrict__ partial) {
    // G[buf][(mt*4+ks)*64 + lane][8]: element (s = mt*16+(lane&15), k' = ks*32+(lane>>4)*8+j)
    __shared__ alignas(16) unsigned short G[2][4 * 4 * 64 * 8];   // 2 x 16384 B
    int t = threadIdx.x, lane = t & 63, w = t >> 6;
    int q = lane >> 4, c16 = lane & 15;
    int blk = blockIdx.x, h = blockIdx.y;
    int bpbase = blk * (BPB * GRP);                // 16 bp per x-block
    const bf16x8* wp = (const bf16x8*)wswz;

    // W fragments resident: rt = cout/16 = h*8 + w*2 + nt
    bf16x8 wreg[5][2];
#pragma unroll
    for (int ks = 0; ks < 5; ks++)
#pragma unroll
        for (int nt = 0; nt < 2; nt++)
            wreg[ks][nt] = wp[((h * 8 + w * 2 + nt) * 5 + ks) * 64 + lane];

    int n_cur[4], n_nxt[4];
#pragma unroll
    for (int mt = 0; mt < 4; mt++)
        n_cur[mt] = idx[(bpbase + (mt >> 1)) * NS + (mt & 1) * 16 + c16];
    {   // stage group 0: wave w stages m-tile w
        int bp = bpbase + (w >> 1);
        const unsigned short* row = featT + ((size_t)(bp >> 11) * N + n_cur[w]) * C + q * 8;
#pragma unroll
        for (int ks = 0; ks < 4; ks++)
            GLOBAL_LOAD_LDS16(row + ks * 32, &G[0][(w * 4 + ks) * 512]);
    }

    float smA[2] = {0.f, 0.f}, sqA[2] = {0.f, 0.f};

    for (int g = 0; g < GRP; g++) {
        int buf = g & 1;
        int bp0 = bpbase + g * BPB;
        if (g + 1 < GRP) {
#pragma unroll
            for (int mt = 0; mt < 4; mt++)
                n_nxt[mt] = idx[(bp0 + BPB + (mt >> 1)) * NS + (mt & 1) * 16 + c16];
        }
        __syncthreads();   // stage(g) drained; compute(g-1) reads of buf^1 done
        if (g + 1 < GRP) {
            int bp = bp0 + BPB + (w >> 1);
            const unsigned short* row = featT + ((size_t)(bp >> 11) * N + n_nxt[w]) * C + q * 8;
#pragma unroll
            for (int ks = 0; ks < 4; ks++)
                GLOBAL_LOAD_LDS16(row + ks * 32, &G[buf ^ 1][(w * 4 + ks) * 512]);
        }

        // ---- compute(g) on G[buf] ----
        f32x4 acc[4][2];
#pragma unroll
        for (int mt = 0; mt < 4; mt++)
#pragma unroll
            for (int nt = 0; nt < 2; nt++) acc[mt][nt] = (f32x4){0.f, 0.f, 0.f, 0.f};

#pragma unroll
        for (int ks = 0; ks < 4; ks++) {
            bf16x8 ag[4];
#pragma unroll
            for (int mt = 0; mt < 4; mt++)
                ag[mt] = *(const bf16x8*)&G[buf][((mt * 4 + ks) * 64 + lane) * 8];
#pragma unroll
            for (int nt = 0; nt < 2; nt++)
#pragma unroll
                for (int mt = 0; mt < 4; mt++)
                    acc[mt][nt] = __builtin_amdgcn_mfma_f32_16x16x32_bf16(ag[mt], wreg[ks][nt], acc[mt][nt], 0, 0, 0);
        }
        // ks = 4: xyz A-frag per mt (built and consumed immediately -> short liveness)
#pragma unroll
        for (int mt = 0; mt < 4; mt++) {
            int bp = bp0 + (mt >> 1);
            unsigned u01 = 0, u23 = 0;
            if (q == 0) {
                const float* src = bbxyz + ((size_t)(bp >> 11) * N + n_cur[mt]) * 3;
                const float* ctr = nxf + bp * 3;
                u01 = (unsigned)f2bf(src[0] - ctr[0]) | ((unsigned)f2bf(src[1] - ctr[1]) << 16);
                u23 = (unsigned)f2bf(src[2] - ctr[2]);
            }
            union { int4 i; bf16x8 hh; } u;
            u.i = make_int4((int)u01, (int)u23, 0, 0);
#pragma unroll
            for (int nt = 0; nt < 2; nt++)
                acc[mt][nt] = __builtin_amdgcn_mfma_f32_16x16x32_bf16(u.hh, wreg[4][nt], acc[mt][nt], 0, 0, 0);
        }

        // ---- epilogue: max over 32 samples (2 m-tiles) per bp; sums accumulate ----
#pragma unroll
        for (int pm = 0; pm < BPB; pm++) {
            int bp = bp0 + pm;
#pragma unroll
            for (int nt = 0; nt < 2; nt++) {
                f32x4 a = acc[2 * pm][nt], c = acc[2 * pm + 1][nt];
                float mx = fmaxf(fmaxf(fmaxf(a[0], a[1]), fmaxf(a[2], a[3])),
                                 fmaxf(fmaxf(c[0], c[1]), fmaxf(c[2], c[3])));
                smA[nt] += ((a[0] + a[1]) + (a[2] + a[3])) + ((c[0] + c[1]) + (c[2] + c[3]));
                sqA[nt] += ((a[0] * a[0] + a[1] * a[1]) + (a[2] * a[2] + a[3] * a[3])) +
                           ((c[0] * c[0] + c[1] * c[1]) + (c[2] * c[2] + c[3] * c[3]));
                mx = fmaxf(mx, __shfl_xor(mx, 16, 64));
                mx = fmaxf(mx, __shfl_xor(mx, 32, 64));
                if (q == 0)
                    ymax[(size_t)bp * COUT + h * 128 + w * 32 + nt * 16 + c16] = mx;
            }
        }
#pragma unroll
        for (int mt = 0; mt < 4; mt++) n_cur[mt] = n_nxt[mt];
    }

    // ---- block-level sum butterfly (once) ----
#pragma unroll
    for (int nt = 0; nt < 2; nt++) {
        float sm = smA[nt], sq = sqA[nt];
        sm += __shfl_xor(sm, 16, 64);
        sm += __shfl_xor(sm, 32, 64);
        sq += __shfl_xor(sq, 16, 64);
        sq += __shfl_xor(sq, 32, 64);
        if (q == 0) {
            int ch = h * 128 + w * 32 + nt * 16 + c16;
            partial[(size_t)blk * 512 + ch] = sm;
            partial[(size_t)blk * 512 + 256 + ch] = sq;
        }
    }
}

// ---------------- K4: fused stat reduce (512x512 partial -> per-channel a,b) --------
__global__ __launch_bounds__(256) void k_stats2(const float* __restrict__ partial,
                                                const float* __restrict__ gam,
                                                const float* __restrict__ bet,
                                                float* __restrict__ ab) {
    int c = threadIdx.x;
    double sm = 0.0, sq = 0.0;
    for (int r = 0; r < NBLK; r++) {
        sm += (double)partial[r * 512 + c];
        sq += (double)partial[r * 512 + 256 + c];
    }
    const double cnt = (double)BP * (double)NS;    // 262144
    double mean = sm / cnt;
    double var = sq / cnt - mean * mean;
    double a = (double)gam[c] / sqrt(var + 1e-5);  // gamma==1 -> a>0 always
    double bb = (double)bet[c] - mean * a;
    ab[c] = (float)a;
    ab[256 + c] = (float)bb;
}

// ---------------- K5: out = relu(a * ymax + b)  (a>0 for all channels) ----------------
__global__ __launch_bounds__(256) void k_final(const float* __restrict__ ymax,
                                               const float* __restrict__ ab,
                                               float* __restrict__ out) {
    int e = blockIdx.x * 256 + threadIdx.x;
    int c = e & 255;
    out[e] = fmaxf(ab[c] * ymax[e] + ab[256 + c], 0.f);
}

extern "C" void kernel_launch(void* const* d_in, const int* in_sizes, int n_in,
                              void* d_out, int out_size, void* d_ws, size_t ws_size,
                              hipStream_t stream) {
    const float* ffps  = (const float*)d_in[0];
    const float* bbxyz = (const float*)d_in[1];
    const float* feat  = (const float*)d_in[2];
    const float* wsh   = (const float*)d_in[3];
    const float* gsh   = (const float*)d_in[4];
    const float* bsh   = (const float*)d_in[5];
    const float* wml   = (const float*)d_in[6];
    const float* gml   = (const float*)d_in[7];
    const float* bml   = (const float*)d_in[8];
    float* out = (float*)d_out;
    char* ws = (char*)d_ws;
    if (ws_size < WS_NEED) return;

    unsigned short* featT = (unsigned short*)(ws + OFF_FEATT);
    unsigned short* wswz  = (unsigned short*)(ws + OFF_WSWZ);
    double*         nxd   = (double*)(ws + OFF_NXD);
    float*          nxf   = (float*)(ws + OFF_NXF);
    int*            idx   = (int*)(ws + OFF_IDX);
    float*          ymax  = (float*)(ws + OFF_YMAX);
    float*          part  = (float*)(ws + OFF_PART);
    float*          ab    = (float*)(ws + OFF_AB);

    k_prep<<<dim3(PREP_NB), dim3(256), 0, stream>>>(feat, featT, wml, wswz,
                                                    ffps, wsh, gsh, bsh, nxd, nxf);
    k_ballq<<<dim3(BP / 4), dim3(256), 0, stream>>>(bbxyz, nxd, idx);
    k_mlp_mfma<<<dim3(NBLK, 2), dim3(256), 0, stream>>>(bbxyz, featT, wswz, nxf, idx, ymax, part);
    k_stats2<<<dim3(1), dim3(256), 0, stream>>>(part, gml, bml, ab);
    k_final<<<dim3(BP * COUT / 256), dim3(256), 0, stream>>>(ymax, ab, out);
}

// Round 11
// 185.348 us; speedup vs baseline: 1.0402x; 1.0402x over previous
//
#include <hip/hip_runtime.h>
#include <math.h>

namespace {
constexpr int B    = 4;
constexpr int N    = 8192;
constexpr int P    = 2048;
constexpr int C    = 128;
constexpr int COUT = 256;
constexpr int NS   = 32;
constexpr int BP   = B * P;     // 8192
constexpr int BPB  = 2;         // bp per group (4 m-tiles)
constexpr int GRP  = 8;         // groups per block (16 bp/block)
constexpr int NBLK = BP / (BPB * GRP); // 512 blocks

// k_prep grid: 2048 transpose + 160 wswz + 1 shift
constexpr int PREP_T = 2048;
constexpr int PREP_W = 160;
constexpr int PREP_NB = PREP_T + PREP_W + 1;   // 2209

// ---- workspace layout (bytes, all 256-aligned) ----
constexpr size_t OFF_FEATT = 0;                          // B*N*C bf16    = 8388608
constexpr size_t OFF_WSWZ  = 8388608;                    // 40960 bf16    = 81920
constexpr size_t OFF_NXD   = 8470528;                    // 8192*3 f64    = 196608
constexpr size_t OFF_NXF   = 8667136;                    // 8192*3 f32    = 98304
constexpr size_t OFF_IDX   = 8765440;                    // 8192*32 i32   = 1048576
constexpr size_t OFF_GXYZP = 9814016;                    // 8192*32*8 bf16= 4194304
constexpr size_t OFF_YMAX  = 14008320;                   // 8192*256 f32  = 8388608
constexpr size_t OFF_PART  = 22396928;                   // 512*512 f32   = 1048576
constexpr size_t OFF_AB    = 23445504;                   // 512 f32       = 2048
constexpr size_t WS_NEED   = 23447552;                   // ~22.4 MB
} // namespace

typedef short bf16x8 __attribute__((ext_vector_type(8)));
typedef float f32x4  __attribute__((ext_vector_type(4)));

typedef const __attribute__((address_space(1))) void gas_void;
typedef __attribute__((address_space(3))) void las_void;
#define GLOBAL_LOAD_LDS16(gp, lp) \
    __builtin_amdgcn_global_load_lds((gas_void*)(gp), (las_void*)(lp), 16, 0, 0)

__device__ inline unsigned short f2bf(float f) {
    unsigned u = __float_as_uint(f);
    unsigned r = u + 0x7fffu + ((u >> 16) & 1u);
    return (unsigned short)(r >> 16);
}

// ---------------- K0: fused prep (all branches PARALLEL — R7 lesson) ----------------
__global__ __launch_bounds__(256) void k_prep(const float* __restrict__ feat,
                                              unsigned short* __restrict__ featT,
                                              const float* __restrict__ wml,
                                              unsigned short* __restrict__ wswz,
                                              const float* __restrict__ ffps,
                                              const float* __restrict__ wsh,
                                              const float* __restrict__ gam,
                                              const float* __restrict__ bet,
                                              double* __restrict__ nxd,
                                              float* __restrict__ nxf) {
    __shared__ float tile[64][33];         // transpose path
    __shared__ double red2[6][4];          // shift path (per-wave partials)
    __shared__ double par2[6];
    int bi = blockIdx.x, t = threadIdx.x;

    if (bi < PREP_T) {
        // ---- transpose: tile 32 n x 64 c ----
        int tx = t & 31, ty = t >> 5;              // 32 x 8
        int n0 = (bi & 255) * 32;
        int rest = bi >> 8;
        int c0 = (rest & 1) * 64, b = rest >> 1;
        const float* src = feat + ((size_t)b * C + c0) * N + n0;
#pragma unroll
        for (int j = 0; j < 8; j++) tile[ty + 8 * j][tx] = src[(size_t)(ty + 8 * j) * N + tx];
        __syncthreads();
#pragma unroll
        for (int j = 0; j < 4; j++) {
            int n = ty + 8 * j;
            unsigned v = (unsigned)f2bf(tile[2 * tx][n]) | ((unsigned)f2bf(tile[2 * tx + 1][n]) << 16);
            *(unsigned*)&featT[((size_t)b * N + n0 + n) * C + c0 + 2 * tx] = v;
        }
    } else if (bi < PREP_T + PREP_W) {
        // ---- wswz (parallel): wswz[rt(16)][ks(5)][lane(64)][j(8)] = W[rt*16+(lane&15)][k'],
        // k' = ks*32+(lane>>4)*8+j; map: k'<128 -> col 3+k'; 128..130 -> col 0..2; else 0
        int i = (bi - PREP_T) * 256 + t;           // < 40960
        int j = i & 7;
        int lane = (i >> 3) & 63;
        int rest = i >> 9;
        int ks = rest % 5, rt = rest / 5;
        int cout = rt * 16 + (lane & 15);
        int k = ks * 32 + (lane >> 4) * 8 + j;
        float v = 0.f;
        if (k < 128) v = wml[cout * 131 + 3 + k];
        else if (k < 131) v = wml[cout * 131 + (k - 128)];
        wswz[i] = f2bf(v);
    } else {
#pragma clang fp contract(off)
        // ---- shift: 256 threads x 32 pts, loads batched x8 so latency pipelines ----
        int lane = t & 63, w = t >> 6;
        double wv[9];
#pragma unroll
        for (int i = 0; i < 9; i++) wv[i] = (double)wsh[i];
        double s[3] = {0, 0, 0}, sq[3] = {0, 0, 0};
        for (int bb = 0; bb < 4; bb++) {
            float f[8][3];
#pragma unroll
            for (int i = 0; i < 8; i++) {
                int p = t + 256 * (bb * 8 + i);
                f[i][0] = ffps[p * 3 + 0]; f[i][1] = ffps[p * 3 + 1]; f[i][2] = ffps[p * 3 + 2];
            }
#pragma unroll
            for (int i = 0; i < 8; i++) {
                double f0 = (double)f[i][0], f1 = (double)f[i][1], f2 = (double)f[i][2];
#pragma unroll
                for (int o = 0; o < 3; o++) {
                    double xo = (wv[o * 3 + 0] * f0 + wv[o * 3 + 1] * f1) + wv[o * 3 + 2] * f2;
                    s[o] += xo;
                    sq[o] += xo * xo;
                }
            }
        }
#pragma unroll
        for (int st = 1; st < 64; st <<= 1) {
#pragma unroll
            for (int o = 0; o < 3; o++) {
                s[o] += __shfl_xor(s[o], st, 64);
                sq[o] += __shfl_xor(sq[o], st, 64);
            }
        }
        if (lane == 0) {
#pragma unroll
            for (int o = 0; o < 3; o++) { red2[o][w] = s[o]; red2[3 + o][w] = sq[o]; }
        }
        __syncthreads();
        if (t == 0) {
#pragma unroll
            for (int o = 0; o < 3; o++) {
                double sm = ((red2[o][0] + red2[o][1]) + (red2[o][2] + red2[o][3]));
                double sqs = ((red2[3 + o][0] + red2[3 + o][1]) + (red2[3 + o][2] + red2[3 + o][3]));
                double m = sm / (double)BP;
                double v = sqs / (double)BP - m * m;
                par2[o] = m;
                par2[3 + o] = 1.0 / sqrt(v + 1e-5);
            }
        }
        __syncthreads();
        double gv[3] = {(double)gam[0], (double)gam[1], (double)gam[2]};
        double bv[3] = {(double)bet[0], (double)bet[1], (double)bet[2]};
        for (int bb = 0; bb < 4; bb++) {
            float f[8][3];
#pragma unroll
            for (int i = 0; i < 8; i++) {
                int p = t + 256 * (bb * 8 + i);
                f[i][0] = ffps[p * 3 + 0]; f[i][1] = ffps[p * 3 + 1]; f[i][2] = ffps[p * 3 + 2];
            }
#pragma unroll
            for (int i = 0; i < 8; i++) {
                int p = t + 256 * (bb * 8 + i);
                double f0 = (double)f[i][0], f1 = (double)f[i][1], f2 = (double)f[i][2];
#pragma unroll
                for (int o = 0; o < 3; o++) {
                    double xo = (wv[o * 3 + 0] * f0 + wv[o * 3 + 1] * f1) + wv[o * 3 + 2] * f2;
                    double y = ((xo - par2[o]) * par2[3 + o]) * gv[o] + bv[o];
                    y = (y > 0.0) ? y : 0.0;
                    nxd[p * 3 + o] = y;
                    nxf[p * 3 + o] = (float)y;
                }
            }
        }
    }
}

// ---------------- K2: ball query + recentered-xyz emission ----------------
// Emits gxyzp[bp][s] = {bf16(x-cx), bf16(y-cy), bf16(z-cz), 0...} (16 B rows) so
// k_mlp can stage the ks=4 A-fragment with the same global_load_lds path as feats
// (kills all xyz VALU + scalar loads in the hot loop). Values bit-identical to the
// R8/R9 in-mlp computation (same fp32 inputs, same f2bf).
__global__ __launch_bounds__(256) void k_ballq(const float* __restrict__ bbxyz,
                                               const double* __restrict__ nxd,
                                               const float* __restrict__ nxf,
                                               int* __restrict__ idxo,
                                               unsigned short* __restrict__ gxyzp) {
#pragma clang fp contract(off)
    int t = threadIdx.x;
    int wv = t >> 6, lane = t & 63;
    int q = blockIdx.x * 4 + wv;                   // bp index
    int b = q >> 11;                               // P = 2048
    double qx = nxd[q * 3 + 0], qy = nxd[q * 3 + 1], qz = nxd[q * 3 + 2];
    float cx = nxf[q * 3 + 0], cy = nxf[q * 3 + 1], cz = nxf[q * 3 + 2];
    const float* base = bbxyz + (size_t)b * N * 3;
    const double R2 = 0.8 * 0.8;
    // early-out: ball misses backbone cube [-1,1]^3 -> zero neighbors -> pad idx 0
    {
        double ex = fmax(fmax(qx - 1.0, -1.0 - qx), 0.0);
        double ey = fmax(fmax(qy - 1.0, -1.0 - qy), 0.0);
        double ez = fmax(fmax(qz - 1.0, -1.0 - qz), 0.0);
        if (ex * ex + ey * ey + ez * ez >= R2) {
            if (lane < NS) {
                idxo[q * NS + lane] = 0;
                float gx = base[0] - cx, gy = base[1] - cy, gz = base[2] - cz;
                uint4 pk = {(unsigned)f2bf(gx) | ((unsigned)f2bf(gy) << 16),
                            (unsigned)f2bf(gz), 0u, 0u};
                *(uint4*)&gxyzp[((size_t)q * NS + lane) * 8] = pk;
            }
            return;
        }
    }
    int found = 0, firstn = -1;

    float px[8], py[8], pz[8];
#pragma unroll
    for (int j = 0; j < 8; j++) {
        int n = j * 64 + lane;
        px[j] = base[n * 3 + 0]; py[j] = base[n * 3 + 1]; pz[j] = base[n * 3 + 2];
    }
    for (int cb = 0; cb < 16; cb++) {
        float nx[8], ny[8], nz[8];
        int nb = (cb + 1 < 16) ? (cb + 1) * 512 : 0;   // clamped -> unconditional prefetch
#pragma unroll
        for (int j = 0; j < 8; j++) {
            int n = nb + j * 64 + lane;
            nx[j] = base[n * 3 + 0]; ny[j] = base[n * 3 + 1]; nz[j] = base[n * 3 + 2];
        }
#pragma unroll
        for (int j = 0; j < 8; j++) {
            int n = cb * 512 + j * 64 + lane;
            double dx = qx - (double)px[j], dy = qy - (double)py[j], dz = qz - (double)pz[j];
            double d2 = (dx * dx + dy * dy) + dz * dz;
            bool within = d2 < R2;
            unsigned long long mask = __ballot(within);
            if (firstn < 0 && mask != 0ull) firstn = (n - lane) + (__ffsll(mask) - 1);
            if (within) {
                int rank = found + __popcll(mask & ((1ull << lane) - 1ull));
                if (rank < NS) {
                    idxo[q * NS + rank] = n;
                    float gx = px[j] - cx, gy = py[j] - cy, gz = pz[j] - cz;
                    uint4 pk = {(unsigned)f2bf(gx) | ((unsigned)f2bf(gy) << 16),
                                (unsigned)f2bf(gz), 0u, 0u};
                    *(uint4*)&gxyzp[((size_t)q * NS + rank) * 8] = pk;
                }
            }
            found += __popcll(mask);
        }
        if (found >= NS) break;
#pragma unroll
        for (int j = 0; j < 8; j++) { px[j] = nx[j]; py[j] = ny[j]; pz[j] = nz[j]; }
    }
    if (found < NS) {
        int padv = (found == 0) ? 0 : firstn;
        if (lane >= found && lane < NS) {
            idxo[q * NS + lane] = padv;
            float gx = base[padv * 3 + 0] - cx;
            float gy = base[padv * 3 + 1] - cy;
            float gz = base[padv * 3 + 2] - cz;
            uint4 pk = {(unsigned)f2bf(gx) | ((unsigned)f2bf(gy) << 16),
                        (unsigned)f2bf(gz), 0u, 0u};
            *(uint4*)&gxyzp[((size_t)q * NS + lane) * 8] = pk;
        }
    }
}

// ---------------- K3: MFMA grouped 1x1 conv — barrier-clean pipeline --------------
// 512 blocks x 8 groups x 2 bp; A = samples (G), B = W^T (couts), nt=4 (no cout
// duplication — R9 lesson: doubling staging bought nothing). All idx in LDS (loaded
// once); per-wave staging indices pre-read into registers -> NO VMEM loads adjacent
// to barriers; xyz staged from gxyzp as a uniform 5th k-step -> no f2bf/branches in
// the hot loop. Lanes q>0 of the ks=4 load read a dummy row: their products hit W's
// structural zeros (k'>=131), garbage is harmless. Barrier drain now only covers
// staging issued a full compute-phase earlier.
__global__ __launch_bounds__(256, 2) void k_mlp_mfma(
        const unsigned short* __restrict__ featT,
        const unsigned short* __restrict__ wswz,
        const unsigned short* __restrict__ gxyzp,
        const int* __restrict__ idx,
        float* __restrict__ ymax,
        float* __restrict__ partial) {
    // G[buf][(mt*5+ks)*64 + lane][8]: element (s = mt*16+(lane&15), k' = ks*32+(lane>>4)*8+j)
    __shared__ alignas(16) unsigned short G[2][4 * 5 * 64 * 8];   // 2 x 20480 B
    __shared__ int sidx[16 * NS];                                  // 2 KB
    int t = threadIdx.x, lane = t & 63, w = t >> 6;
    int q = lane >> 4, c16 = lane & 15;
    int blk = blockIdx.x;
    int bpbase = blk * (BPB * GRP);                // 16 bp per block
    const bf16x8* wp = (const bf16x8*)wswz;

    // block's idx -> LDS (one coalesced int2 per thread)
    ((int2*)sidx)[t] = ((const int2*)(idx + (size_t)bpbase * NS))[t];

    // W fragments resident in registers
    bf16x8 wreg[5][4];
#pragma unroll
    for (int ks = 0; ks < 5; ks++)
#pragma unroll
        for (int nt = 0; nt < 4; nt++)
            wreg[ks][nt] = wp[((w * 4 + nt) * 5 + ks) * 64 + lane];

    __syncthreads();                               // sidx visible

    // per-wave staging indices for all 8 groups (wave w stages m-tile w)
    int lbp_w = w >> 1;                            // bp within group pair
    int soff = (w & 1) * 16 + c16;                 // sample within bp
    int n_all[8];
#pragma unroll
    for (int g = 0; g < 8; g++)
        n_all[g] = sidx[(g * 2 + lbp_w) * NS + soff];

    // stage group 0
    {
        int bp = bpbase + lbp_w;
        const unsigned short* row = featT + ((size_t)(bp >> 11) * N + n_all[0]) * C + q * 8;
#pragma unroll
        for (int ks = 0; ks < 4; ks++)
            GLOBAL_LOAD_LDS16(row + ks * 32, &G[0][(w * 5 + ks) * 512]);
        size_t grow = (q == 0) ? ((size_t)bp * NS + soff) : 0;
        GLOBAL_LOAD_LDS16(gxyzp + grow * 8, &G[0][(w * 5 + 4) * 512]);
    }

    float smA[4] = {0.f, 0.f, 0.f, 0.f}, sqA[4] = {0.f, 0.f, 0.f, 0.f};

    for (int g = 0; g < GRP; g++) {
        int buf = g & 1;
        int bp0 = bpbase + g * BPB;
        __syncthreads();   // stage(g) drained; compute(g-1) reads of buf^1 done
        if (g + 1 < GRP) {
            int bp = bp0 + BPB + lbp_w;
            const unsigned short* row = featT + ((size_t)(bp >> 11) * N + n_all[g + 1]) * C + q * 8;
#pragma unroll
            for (int ks = 0; ks < 4; ks++)
                GLOBAL_LOAD_LDS16(row + ks * 32, &G[buf ^ 1][(w * 5 + ks) * 512]);
            size_t grow = (q == 0) ? ((size_t)bp * NS + soff) : 0;
            GLOBAL_LOAD_LDS16(gxyzp + grow * 8, &G[buf ^ 1][(w * 5 + 4) * 512]);
        }

        // ---- compute(g) on G[buf]: uniform 5 k-steps ----
        f32x4 acc[4][4];
#pragma unroll
        for (int mt = 0; mt < 4; mt++)
#pragma unroll
            for (int nt = 0; nt < 4; nt++) acc[mt][nt] = (f32x4){0.f, 0.f, 0.f, 0.f};

#pragma unroll
        for (int ks = 0; ks < 5; ks++) {
            bf16x8 ag[4];
#pragma unroll
            for (int mt = 0; mt < 4; mt++)
                ag[mt] = *(const bf16x8*)&G[buf][((mt * 5 + ks) * 64 + lane) * 8];
#pragma unroll
            for (int nt = 0; nt < 4; nt++)
#pragma unroll
                for (int mt = 0; mt < 4; mt++)
                    acc[mt][nt] = __builtin_amdgcn_mfma_f32_16x16x32_bf16(ag[mt], wreg[ks][nt], acc[mt][nt], 0, 0, 0);
        }

        // ---- epilogue: max over 32 samples (2 m-tiles) per bp; sums accumulate ----
#pragma unroll
        for (int pm = 0; pm < BPB; pm++) {
            int bp = bp0 + pm;
#pragma unroll
            for (int nt = 0; nt < 4; nt++) {
                f32x4 a = acc[2 * pm][nt], c = acc[2 * pm + 1][nt];
                float mx = fmaxf(fmaxf(fmaxf(a[0], a[1]), fmaxf(a[2], a[3])),
                                 fmaxf(fmaxf(c[0], c[1]), fmaxf(c[2], c[3])));
                smA[nt] += ((a[0] + a[1]) + (a[2] + a[3])) + ((c[0] + c[1]) + (c[2] + c[3]));
                sqA[nt] += ((a[0] * a[0] + a[1] * a[1]) + (a[2] * a[2] + a[3] * a[3])) +
                           ((c[0] * c[0] + c[1] * c[1]) + (c[2] * c[2] + c[3] * c[3]));
                mx = fmaxf(mx, __shfl_xor(mx, 16, 64));
                mx = fmaxf(mx, __shfl_xor(mx, 32, 64));
                if (q == 0)
                    ymax[(size_t)bp * COUT + w * 64 + nt * 16 + c16] = mx;
            }
        }
    }

    // ---- block-level sum butterfly (once) ----
#pragma unroll
    for (int nt = 0; nt < 4; nt++) {
        float sm = smA[nt], sq = sqA[nt];
        sm += __shfl_xor(sm, 16, 64);
        sm += __shfl_xor(sm, 32, 64);
        sq += __shfl_xor(sq, 16, 64);
        sq += __shfl_xor(sq, 32, 64);
        if (q == 0) {
            int cout = w * 64 + nt * 16 + c16;
            partial[(size_t)blk * 512 + cout] = sm;
            partial[(size_t)blk * 512 + 256 + cout] = sq;
        }
    }
}

// ---------------- K4: fused stat reduce (512x512 partial -> per-channel a,b) --------
__global__ __launch_bounds__(256) void k_stats2(const float* __restrict__ partial,
                                                const float* __restrict__ gam,
                                                const float* __restrict__ bet,
                                                float* __restrict__ ab) {
    int c = threadIdx.x;
    double sm = 0.0, sq = 0.0;
    for (int r = 0; r < NBLK; r++) {
        sm += (double)partial[r * 512 + c];
        sq += (double)partial[r * 512 + 256 + c];
    }
    const double cnt = (double)BP * (double)NS;    // 262144
    double mean = sm / cnt;
    double var = sq / cnt - mean * mean;
    double a = (double)gam[c] / sqrt(var + 1e-5);  // gamma==1 -> a>0 always
    double bb = (double)bet[c] - mean * a;
    ab[c] = (float)a;
    ab[256 + c] = (float)bb;
}

// ---------------- K5: out = relu(a * ymax + b)  (a>0 for all channels) ----------------
__global__ __launch_bounds__(256) void k_final(const float* __restrict__ ymax,
                                               const float* __restrict__ ab,
                                               float* __restrict__ out) {
    int e = blockIdx.x * 256 + threadIdx.x;
    int c = e & 255;
    out[e] = fmaxf(ab[c] * ymax[e] + ab[256 + c], 0.f);
}

extern "C" void kernel_launch(void* const* d_in, const int* in_sizes, int n_in,
                              void* d_out, int out_size, void* d_ws, size_t ws_size,
                              hipStream_t stream) {
    const float* ffps  = (const float*)d_in[0];
    const float* bbxyz = (const float*)d_in[1];
    const float* feat  = (const float*)d_in[2];
    const float* wsh   = (const float*)d_in[3];
    const float* gsh   = (const float*)d_in[4];
    const float* bsh   = (const float*)d_in[5];
    const float* wml   = (const float*)d_in[6];
    const float* gml   = (const float*)d_in[7];
    const float* bml   = (const float*)d_in[8];
    float* out = (float*)d_out;
    char* ws = (char*)d_ws;
    if (ws_size < WS_NEED) return;

    unsigned short* featT = (unsigned short*)(ws + OFF_FEATT);
    unsigned short* wswz  = (unsigned short*)(ws + OFF_WSWZ);
    double*         nxd   = (double*)(ws + OFF_NXD);
    float*          nxf   = (float*)(ws + OFF_NXF);
    int*            idx   = (int*)(ws + OFF_IDX);
    unsigned short* gxyzp = (unsigned short*)(ws + OFF_GXYZP);
    float*          ymax  = (float*)(ws + OFF_YMAX);
    float*          part  = (float*)(ws + OFF_PART);
    float*          ab    = (float*)(ws + OFF_AB);

    k_prep<<<dim3(PREP_NB), dim3(256), 0, stream>>>(feat, featT, wml, wswz,
                                                    ffps, wsh, gsh, bsh, nxd, nxf);
    k_ballq<<<dim3(BP / 4), dim3(256), 0, stream>>>(bbxyz, nxd, nxf, idx, gxyzp);
    k_mlp_mfma<<<dim3(NBLK), dim3(256), 0, stream>>>(featT, wswz, gxyzp, idx, ymax, part);
    k_stats2<<<dim3(1), dim3(256), 0, stream>>>(part, gml, bml, ab);
    k_final<<<dim3(BP * COUT / 256), dim3(256), 0, stream>>>(ymax, ab, out);
}